// Round 29
// baseline (361.488 us; speedup 1.0000x reference)
//
#include <hip/hip_runtime.h>

// Problem constants: B=4096, K=16, H=32, HM=128, STEPS=8
#define OFF_MS  524288
#define OFF_CS  557056
#define OFF_IP  1081344
#define OFF_CUM 1179648
#define OFF_EPS 1183744

#define HSTR 136
#define BSTR 40

// d_ws layout (u16): bf16 weights transposed to [n][k]
#define WA_PTP 0
#define WB_PTA 4096
#define WC_PTA 8192
#define WA_CAP 12288
#define WB_CAA 16384
#define WC_CAA 20480
#define WH_PTP 24576
#define WH_CAP 28672
#define WF1    32768
#define WF2    33792
#define WF3    34816
#define WQKV   35840
#define WKK    38912
#define WVV    39936

struct Params {
  const float *knn, *query, *fw1, *fb1, *fw2, *fb2, *fw3, *fb3, *qkv_w,
    *ptp_w1, *ptp_b1, *ptp_w2, *ptp_b2, *pta_w1, *pta_b1, *pta_w2, *pta_b2,
    *caq_w, *caq_b, *cak_w, *cak_b, *cav_w, *cav_b,
    *cap_w1, *cap_b1, *cap_w2, *cap_b2, *caa_w1, *caa_b1, *caa_w2, *caa_b2,
    *im_w1, *im_b1, *im_w2, *im_b2, *im_w3, *im_b3,
    *ep_w1, *ep_b1, *ep_w2, *ep_b2, *ep_w3, *ep_b3;
  float *o_ld, *o_ms, *o_cs, *o_ip, *o_cum, *o_eps;
};
static_assert(sizeof(Params) == 49 * sizeof(void*), "Params layout");

typedef float f32x4 __attribute__((ext_vector_type(4)));
typedef short s16x8 __attribute__((ext_vector_type(8)));

__device__ __forceinline__ unsigned short f2b(float x) {
  unsigned u = __float_as_uint(x);
  u += 0x7fffu + ((u >> 16) & 1u);
  return (unsigned short)(u >> 16);
}
__device__ __forceinline__ float b2f(unsigned short x) {
  return __uint_as_float((unsigned)x << 16);
}
__device__ __forceinline__ unsigned pack2(float lo, float hi) {
  return (unsigned)f2b(lo) | ((unsigned)f2b(hi) << 16);
}

#define MFMA(acc, a, bb) \
  (acc = __builtin_amdgcn_mfma_f32_16x16x32_bf16((a), (bb), (acc), 0, 0, 0))
#define PRIO_HI() __builtin_amdgcn_s_setprio(1)
#define PRIO_LO() __builtin_amdgcn_s_setprio(0)

__global__ void prep_kernel(Params p, unsigned short* ws) {
  const int t = blockIdx.x * 256 + threadIdx.x;
  const int n = t >> 7, k = t & 127;
  ws[WA_PTP + t] = f2b(p.ptp_w2[k * 32 + n]);
  ws[WC_PTA + t] = f2b(p.pta_w2[k * 32 + n]);
  ws[WA_CAP + t] = f2b(p.cap_w2[k * 32 + n]);
  ws[WC_CAA + t] = f2b(p.caa_w2[k * 32 + n]);
  const int n2 = t >> 5, k2 = t & 31;
  ws[WB_PTA + t] = f2b(p.pta_w1[k2 * 128 + n2]);
  ws[WB_CAA + t] = f2b(p.caa_w1[k2 * 128 + n2]);
  ws[WH_PTP + t] = (k2 < 3) ? f2b(p.ptp_w1[k2 * 128 + n2])
                  : (k2 == 3 ? f2b(p.ptp_b1[n2]) : (unsigned short)0);
  ws[WH_CAP + t] = (k2 < 3) ? f2b(p.cap_w1[k2 * 128 + n2])
                  : (k2 == 3 ? f2b(p.cap_b1[n2]) : (unsigned short)0);
  if (t < 1024) {
    ws[WF1 + t] = (k2 < 3) ? f2b(p.fw1[k2 * 32 + n2])
                 : (k2 == 3 ? f2b(p.fb1[n2]) : (unsigned short)0);
    ws[WF2 + t] = f2b(p.fw2[k2 * 32 + n2]);
    ws[WF3 + t] = f2b(p.fw3[k2 * 32 + n2]);
    ws[WKK + t] = f2b(p.cak_w[k2 * 32 + n2]);
    ws[WVV + t] = f2b(p.cav_w[k2 * 32 + n2]);
  }
  if (t < 3072) ws[WQKV + t] = f2b(p.qkv_w[k2 * 96 + n2]);
}

// Round-28 (builtin MFMA + setprio, 228us) with launch_bounds relaxed
// (64,2)->(64,1): occupancy is LDS-bound (20480B x 8 blocks = 160KiB ->
// 2 waves/SIMD regardless), so the 128-VGPR cap only caused spill + limited
// scheduler hoisting depth. Allocator may now use up to 256 VGPR while
// keeping 2 waves/SIMD.
__launch_bounds__(64, 1)
__global__ void puray_kernel(Params p, const unsigned short* ws) {
  const int b0 = blockIdx.x * 2;
  const int l = threadIdx.x;
  const int ln16 = l & 15, kg = l >> 4, k0 = kg * 8;
  const int gH = l >> 5, lh = l & 31;   // half id = batch for scalar parts

  __shared__ __align__(16) unsigned short s_workA[16 * HSTR];
  __shared__ __align__(16) unsigned short s_workB[16 * HSTR];
  __shared__ __align__(16) unsigned short s_simbA[16 * BSTR];
  __shared__ __align__(16) unsigned short s_simbB[16 * BSTR];
  __shared__ __align__(16) unsigned short s_featb[2][16 * BSTR];
  __shared__ __align__(16) unsigned short s_ub[2][1024];  // bf16 q|k / kk|vv
  __shared__ __align__(16) unsigned short s_vb[512];      // bf16 v (per-batch C)
  __shared__ float s_coords[2][48], s_relv[2][48], s_reld[2][16];
  __shared__ float s_qry[2][3], s_op[2][3], s_qq[2][32], s_ca[2][32];
  __shared__ float s_cum[2];

  for (int idx = l; idx < 96; idx += 64) s_coords[idx / 48][idx % 48] = p.knn[b0 * 48 + idx];
  if (l < 6) s_qry[l / 3][l % 3] = p.query[b0 * 3 + l];
  else if (l < 8) s_cum[l - 6] = 0.f;
  else if (l < 14) s_op[(l - 8) / 3][(l - 8) % 3] = 0.f;
  __syncthreads();

  // ================= Phases A/B/C + kkvv per batch =================
  for (int g = 0; g < 2; ++g) {
    const float* cg = s_coords[g];
    {  // A-L1: coords -> h1 (s_simbA)
      union { s16x8 v; unsigned u[4]; } cv;
      cv.u[0] = (kg == 0) ? pack2(cg[ln16 * 3 + 0], cg[ln16 * 3 + 1]) : 0u;
      cv.u[1] = (kg == 0) ? pack2(cg[ln16 * 3 + 2], 1.0f) : 0u;
      cv.u[2] = 0u; cv.u[3] = 0u;
      const s16x8 af = cv.v;
      const s16x8 w0 = *(const s16x8*)&ws[WF1 + (0 * 16 + ln16) * 32 + k0];
      const s16x8 w1 = *(const s16x8*)&ws[WF1 + (1 * 16 + ln16) * 32 + k0];
      f32x4 A0 = {0.f,0.f,0.f,0.f}, A1 = {0.f,0.f,0.f,0.f};
      PRIO_HI();
      MFMA(A0, af, w0); MFMA(A1, af, w1);
      PRIO_LO();
#pragma unroll
      for (int r2 = 0; r2 < 4; ++r2) {
        const int row = (kg * 4 + r2) * BSTR;
        s_simbA[row + 0 * 16 + ln16] = f2b(fmaxf(A0[r2], 0.f));
        s_simbA[row + 1 * 16 + ln16] = f2b(fmaxf(A1[r2], 0.f));
      }
    }
    {  // A-L2: h1 -> h2 (s_workA)
      const s16x8 af = *(const s16x8*)&s_simbA[ln16 * BSTR + k0];
      const s16x8 w0 = *(const s16x8*)&ws[WF2 + (0 * 16 + ln16) * 32 + k0];
      const s16x8 w1 = *(const s16x8*)&ws[WF2 + (1 * 16 + ln16) * 32 + k0];
      const float b0v = p.fb2[ln16], b1v = p.fb2[16 + ln16];
      f32x4 A0 = {b0v,b0v,b0v,b0v}, A1 = {b1v,b1v,b1v,b1v};
      PRIO_HI();
      MFMA(A0, af, w0); MFMA(A1, af, w1);
      PRIO_LO();
#pragma unroll
      for (int r2 = 0; r2 < 4; ++r2) {
        const int row = (kg * 4 + r2) * HSTR;
        s_workA[row + 0 * 16 + ln16] = f2b(fmaxf(A0[r2], 0.f));
        s_workA[row + 1 * 16 + ln16] = f2b(fmaxf(A1[r2], 0.f));
      }
    }
    {  // A-L3: h2 -> feats (s_featb[g])
      const s16x8 af = *(const s16x8*)&s_workA[ln16 * HSTR + k0];
      const s16x8 w0 = *(const s16x8*)&ws[WF3 + (0 * 16 + ln16) * 32 + k0];
      const s16x8 w1 = *(const s16x8*)&ws[WF3 + (1 * 16 + ln16) * 32 + k0];
      const float b0v = p.fb3[ln16], b1v = p.fb3[16 + ln16];
      f32x4 A0 = {b0v,b0v,b0v,b0v}, A1 = {b1v,b1v,b1v,b1v};
      PRIO_HI();
      MFMA(A0, af, w0); MFMA(A1, af, w1);
      PRIO_LO();
#pragma unroll
      for (int r2 = 0; r2 < 4; ++r2) {
        const int row = (kg * 4 + r2) * BSTR;
        s_featb[g][row + 0 * 16 + ln16] = f2b(A0[r2]);
        s_featb[g][row + 1 * 16 + ln16] = f2b(A1[r2]);
      }
    }
    {  // B: qkv -> s_ub[g] (q|k, bf16) + s_vb (bf16)
      const s16x8 af = *(const s16x8*)&s_featb[g][ln16 * BSTR + k0];
#pragma unroll
      for (int g6 = 0; g6 < 2; ++g6) {
        const int nb0 = g6 * 3;
        const s16x8 w0 = *(const s16x8*)&ws[WQKV + ((nb0 + 0) * 16 + ln16) * 32 + k0];
        const s16x8 w1 = *(const s16x8*)&ws[WQKV + ((nb0 + 1) * 16 + ln16) * 32 + k0];
        const s16x8 w2 = *(const s16x8*)&ws[WQKV + ((nb0 + 2) * 16 + ln16) * 32 + k0];
        f32x4 A0 = {0.f,0.f,0.f,0.f}, A1 = {0.f,0.f,0.f,0.f}, A2 = {0.f,0.f,0.f,0.f};
        PRIO_HI();
        MFMA(A0, af, w0); MFMA(A1, af, w1); MFMA(A2, af, w2);
        PRIO_LO();
#pragma unroll
        for (int j6 = 0; j6 < 3; ++j6) {
          const int o = (nb0 + j6) * 16 + ln16;
          const f32x4 acc = (j6 == 0) ? A0 : (j6 == 1) ? A1 : A2;
#pragma unroll
          for (int r2 = 0; r2 < 4; ++r2) {
            const int row = kg * 4 + r2;
            if (o < 32) s_ub[g][row * 32 + o] = f2b(acc[r2]);
            else if (o < 64) s_ub[g][512 + row * 32 + o - 32] = f2b(acc[r2]);
            else s_vb[row * 32 + o - 64] = f2b(acc[r2]);
          }
        }
      }
    }
    // ---- Phase C (dual-i streams within batch g) ----
    {
      const float* b2c = p.ptp_b2;
      const float* bh1 = p.pta_b1;
      const float* bh2 = p.pta_b2;
      const unsigned short* wsc = ws;
      for (int ip = 0; ip < 8; ++ip) {
        asm volatile("" : "+s"(b2c), "+s"(bh1), "+s"(bh2), "+s"(wsc));
        const int i0 = ip * 2, i1 = ip * 2 + 1;
        const float c00 = cg[i0 * 3 + 0] - cg[ln16 * 3 + 0];
        const float c01 = cg[i0 * 3 + 1] - cg[ln16 * 3 + 1];
        const float c02 = cg[i0 * 3 + 2] - cg[ln16 * 3 + 2];
        const float c10 = cg[i1 * 3 + 0] - cg[ln16 * 3 + 0];
        const float c11 = cg[i1 * 3 + 1] - cg[ln16 * 3 + 1];
        const float c12 = cg[i1 * 3 + 2] - cg[ln16 * 3 + 2];
        {  // hv dual: 4-n-tile groups
          union { s16x8 v; unsigned u[4]; } cv0, cv1;
          cv0.u[0] = (kg == 0) ? pack2(c00, c01) : 0u;
          cv0.u[1] = (kg == 0) ? pack2(c02, 1.0f) : 0u;
          cv0.u[2] = 0u; cv0.u[3] = 0u;
          cv1.u[0] = (kg == 0) ? pack2(c10, c11) : 0u;
          cv1.u[1] = (kg == 0) ? pack2(c12, 1.0f) : 0u;
          cv1.u[2] = 0u; cv1.u[3] = 0u;
          const s16x8 af0 = cv0.v, af1 = cv1.v;
#pragma unroll
          for (int g2b = 0; g2b < 2; ++g2b) {
            const int nbase = g2b * 4;
            const s16x8 w0 = *(const s16x8*)&wsc[WH_PTP + ((nbase + 0) * 16 + ln16) * 32 + k0];
            const s16x8 w1 = *(const s16x8*)&wsc[WH_PTP + ((nbase + 1) * 16 + ln16) * 32 + k0];
            const s16x8 w2 = *(const s16x8*)&wsc[WH_PTP + ((nbase + 2) * 16 + ln16) * 32 + k0];
            const s16x8 w3 = *(const s16x8*)&wsc[WH_PTP + ((nbase + 3) * 16 + ln16) * 32 + k0];
            f32x4 A00 = {0.f,0.f,0.f,0.f}, A01 = {0.f,0.f,0.f,0.f};
            f32x4 A02 = {0.f,0.f,0.f,0.f}, A03 = {0.f,0.f,0.f,0.f};
            f32x4 A10 = {0.f,0.f,0.f,0.f}, A11 = {0.f,0.f,0.f,0.f};
            f32x4 A12 = {0.f,0.f,0.f,0.f}, A13 = {0.f,0.f,0.f,0.f};
            PRIO_HI();
            MFMA(A00, af0, w0); MFMA(A10, af1, w0);
            MFMA(A01, af0, w1); MFMA(A11, af1, w1);
            MFMA(A02, af0, w2); MFMA(A12, af1, w2);
            MFMA(A03, af0, w3); MFMA(A13, af1, w3);
            PRIO_LO();
#pragma unroll
            for (int r2 = 0; r2 < 4; ++r2) {
              const int row = (kg * 4 + r2) * HSTR;
              s_workA[row + (nbase + 0) * 16 + ln16] = f2b(fmaxf(A00[r2], 0.f));
              s_workA[row + (nbase + 1) * 16 + ln16] = f2b(fmaxf(A01[r2], 0.f));
              s_workA[row + (nbase + 2) * 16 + ln16] = f2b(fmaxf(A02[r2], 0.f));
              s_workA[row + (nbase + 3) * 16 + ln16] = f2b(fmaxf(A03[r2], 0.f));
              s_workB[row + (nbase + 0) * 16 + ln16] = f2b(fmaxf(A10[r2], 0.f));
              s_workB[row + (nbase + 1) * 16 + ln16] = f2b(fmaxf(A11[r2], 0.f));
              s_workB[row + (nbase + 2) * 16 + ln16] = f2b(fmaxf(A12[r2], 0.f));
              s_workB[row + (nbase + 3) * 16 + ln16] = f2b(fmaxf(A13[r2], 0.f));
            }
          }
        }
        f32x4 rpe00, rpe01, rpe10, rpe11;
        {  // G1 dual: batched B, staggered A pairs
#pragma unroll
          for (int nb = 0; nb < 2; ++nb) {
            const int n = nb * 16 + ln16;
            const s16x8 w0 = *(const s16x8*)&wsc[WA_PTP + n * 128 + 0 * 32 + k0];
            const s16x8 w1 = *(const s16x8*)&wsc[WA_PTP + n * 128 + 1 * 32 + k0];
            const s16x8 w2 = *(const s16x8*)&wsc[WA_PTP + n * 128 + 2 * 32 + k0];
            const s16x8 w3 = *(const s16x8*)&wsc[WA_PTP + n * 128 + 3 * 32 + k0];
            const float bias = b2c[n];
            f32x4 acc0 = {bias, bias, bias, bias};
            f32x4 acc1 = {bias, bias, bias, bias};
            PRIO_HI();
            {
              const s16x8 a0 = *(const s16x8*)&s_workA[ln16 * HSTR + 0 * 32 + k0];
              const s16x8 a1 = *(const s16x8*)&s_workB[ln16 * HSTR + 0 * 32 + k0];
              MFMA(acc0, a0, w0); MFMA(acc1, a1, w0);
            }
            {
              const s16x8 a0 = *(const s16x8*)&s_workA[ln16 * HSTR + 1 * 32 + k0];
              const s16x8 a1 = *(const s16x8*)&s_workB[ln16 * HSTR + 1 * 32 + k0];
              MFMA(acc0, a0, w1); MFMA(acc1, a1, w1);
            }
            {
              const s16x8 a0 = *(const s16x8*)&s_workA[ln16 * HSTR + 2 * 32 + k0];
              const s16x8 a1 = *(const s16x8*)&s_workB[ln16 * HSTR + 2 * 32 + k0];
              MFMA(acc0, a0, w2); MFMA(acc1, a1, w2);
            }
            {
              const s16x8 a0 = *(const s16x8*)&s_workA[ln16 * HSTR + 3 * 32 + k0];
              const s16x8 a1 = *(const s16x8*)&s_workB[ln16 * HSTR + 3 * 32 + k0];
              MFMA(acc0, a0, w3); MFMA(acc1, a1, w3);
            }
            PRIO_LO();
            if (nb == 0) { rpe00 = acc0; rpe10 = acc1; }
            else { rpe01 = acc0; rpe11 = acc1; }
#pragma unroll
            for (int r2 = 0; r2 < 4; ++r2) {
              const int j = kg * 4 + r2;
              s_simbA[j * BSTR + n] =
                f2b(b2f(s_ub[g][i0 * 32 + n]) - b2f(s_ub[g][512 + j * 32 + n]) + acc0[r2]);
              s_simbB[j * BSTR + n] =
                f2b(b2f(s_ub[g][i1 * 32 + n]) - b2f(s_ub[g][512 + j * 32 + n]) + acc1[r2]);
            }
          }
        }
        {  // G2 dual: 4-n-tile groups
          const s16x8 as0 = *(const s16x8*)&s_simbA[ln16 * BSTR + k0];
          const s16x8 as1 = *(const s16x8*)&s_simbB[ln16 * BSTR + k0];
#pragma unroll
          for (int g2b = 0; g2b < 2; ++g2b) {
            const int nbase = g2b * 4;
            const s16x8 w0 = *(const s16x8*)&wsc[WB_PTA + ((nbase + 0) * 16 + ln16) * 32 + k0];
            const s16x8 w1 = *(const s16x8*)&wsc[WB_PTA + ((nbase + 1) * 16 + ln16) * 32 + k0];
            const s16x8 w2 = *(const s16x8*)&wsc[WB_PTA + ((nbase + 2) * 16 + ln16) * 32 + k0];
            const s16x8 w3 = *(const s16x8*)&wsc[WB_PTA + ((nbase + 3) * 16 + ln16) * 32 + k0];
            const float b0v = bh1[(nbase + 0) * 16 + ln16];
            const float b1v = bh1[(nbase + 1) * 16 + ln16];
            const float b2v = bh1[(nbase + 2) * 16 + ln16];
            const float b3v = bh1[(nbase + 3) * 16 + ln16];
            f32x4 A00 = {b0v,b0v,b0v,b0v}, A01 = {b1v,b1v,b1v,b1v};
            f32x4 A02 = {b2v,b2v,b2v,b2v}, A03 = {b3v,b3v,b3v,b3v};
            f32x4 A10 = {b0v,b0v,b0v,b0v}, A11 = {b1v,b1v,b1v,b1v};
            f32x4 A12 = {b2v,b2v,b2v,b2v}, A13 = {b3v,b3v,b3v,b3v};
            PRIO_HI();
            MFMA(A00, as0, w0); MFMA(A10, as1, w0);
            MFMA(A01, as0, w1); MFMA(A11, as1, w1);
            MFMA(A02, as0, w2); MFMA(A12, as1, w2);
            MFMA(A03, as0, w3); MFMA(A13, as1, w3);
            PRIO_LO();
#pragma unroll
            for (int r2 = 0; r2 < 4; ++r2) {
              const int row = (kg * 4 + r2) * HSTR;
              s_workA[row + (nbase + 0) * 16 + ln16] = f2b(fmaxf(A00[r2], 0.f));
              s_workA[row + (nbase + 1) * 16 + ln16] = f2b(fmaxf(A01[r2], 0.f));
              s_workA[row + (nbase + 2) * 16 + ln16] = f2b(fmaxf(A02[r2], 0.f));
              s_workA[row + (nbase + 3) * 16 + ln16] = f2b(fmaxf(A03[r2], 0.f));
              s_workB[row + (nbase + 0) * 16 + ln16] = f2b(fmaxf(A10[r2], 0.f));
              s_workB[row + (nbase + 1) * 16 + ln16] = f2b(fmaxf(A11[r2], 0.f));
              s_workB[row + (nbase + 2) * 16 + ln16] = f2b(fmaxf(A12[r2], 0.f));
              s_workB[row + (nbase + 3) * 16 + ln16] = f2b(fmaxf(A13[r2], 0.f));
            }
          }
        }
        {  // G3 dual + softmax (batched B, staggered h pairs)
#pragma unroll
          for (int nb = 0; nb < 2; ++nb) {
            const int n = nb * 16 + ln16;
            const s16x8 w0 = *(const s16x8*)&wsc[WC_PTA + n * 128 + 0 * 32 + k0];
            const s16x8 w1 = *(const s16x8*)&wsc[WC_PTA + n * 128 + 1 * 32 + k0];
            const s16x8 w2 = *(const s16x8*)&wsc[WC_PTA + n * 128 + 2 * 32 + k0];
            const s16x8 w3 = *(const s16x8*)&wsc[WC_PTA + n * 128 + 3 * 32 + k0];
            const float bias = bh2[n];
            f32x4 acc0 = {bias, bias, bias, bias};
            f32x4 acc1 = {bias, bias, bias, bias};
            PRIO_HI();
            {
              const s16x8 h0 = *(const s16x8*)&s_workA[ln16 * HSTR + 0 * 32 + k0];
              const s16x8 h1 = *(const s16x8*)&s_workB[ln16 * HSTR + 0 * 32 + k0];
              MFMA(acc0, h0, w0); MFMA(acc1, h1, w0);
            }
            {
              const s16x8 h0 = *(const s16x8*)&s_workA[ln16 * HSTR + 1 * 32 + k0];
              const s16x8 h1 = *(const s16x8*)&s_workB[ln16 * HSTR + 1 * 32 + k0];
              MFMA(acc0, h0, w1); MFMA(acc1, h1, w1);
            }
            {
              const s16x8 h0 = *(const s16x8*)&s_workA[ln16 * HSTR + 2 * 32 + k0];
              const s16x8 h1 = *(const s16x8*)&s_workB[ln16 * HSTR + 2 * 32 + k0];
              MFMA(acc0, h0, w2); MFMA(acc1, h1, w2);
            }
            {
              const s16x8 h0 = *(const s16x8*)&s_workA[ln16 * HSTR + 3 * 32 + k0];
              const s16x8 h1 = *(const s16x8*)&s_workB[ln16 * HSTR + 3 * 32 + k0];
              MFMA(acc0, h0, w3); MFMA(acc1, h1, w3);
            }
            PRIO_LO();
            const f32x4 rp0 = nb ? rpe01 : rpe00;
            const f32x4 rp1 = nb ? rpe11 : rpe10;
            float mx = fmaxf(fmaxf(acc0[0], acc0[1]), fmaxf(acc0[2], acc0[3]));
            mx = fmaxf(mx, __shfl_xor(mx, 16));
            mx = fmaxf(mx, __shfl_xor(mx, 32));
            float sum = 0.f, o = 0.f;
#pragma unroll
            for (int r2 = 0; r2 < 4; ++r2) {
              const int j = kg * 4 + r2;
              const float e = __expf(acc0[r2] - mx);
              sum += e;
              o = fmaf(e, b2f(s_vb[j * 32 + n]) + rp0[r2], o);
            }
            sum += __shfl_xor(sum, 16); o += __shfl_xor(o, 16);
            sum += __shfl_xor(sum, 32); o += __shfl_xor(o, 32);
            if (kg == 0) s_featb[g][i0 * BSTR + n] = f2b(o / sum);
            float mx1 = fmaxf(fmaxf(acc1[0], acc1[1]), fmaxf(acc1[2], acc1[3]));
            mx1 = fmaxf(mx1, __shfl_xor(mx1, 16));
            mx1 = fmaxf(mx1, __shfl_xor(mx1, 32));
            float sum1 = 0.f, o1 = 0.f;
#pragma unroll
            for (int r2 = 0; r2 < 4; ++r2) {
              const int j = kg * 4 + r2;
              const float e = __expf(acc1[r2] - mx1);
              sum1 += e;
              o1 = fmaf(e, b2f(s_vb[j * 32 + n]) + rp1[r2], o1);
            }
            sum1 += __shfl_xor(sum1, 16); o1 += __shfl_xor(o1, 16);
            sum1 += __shfl_xor(sum1, 32); o1 += __shfl_xor(o1, 32);
            if (kg == 0) s_featb[g][i1 * BSTR + n] = f2b(o1 / sum1);
          }
        }
      }
    }
    // ---- kk / vvb for batch g ----
    {
      const s16x8 af = *(const s16x8*)&s_featb[g][ln16 * BSTR + k0];
      const s16x8 wk0 = *(const s16x8*)&ws[WKK + (0 * 16 + ln16) * 32 + k0];
      const s16x8 wk1 = *(const s16x8*)&ws[WKK + (1 * 16 + ln16) * 32 + k0];
      const s16x8 wv0 = *(const s16x8*)&ws[WVV + (0 * 16 + ln16) * 32 + k0];
      const s16x8 wv1 = *(const s16x8*)&ws[WVV + (1 * 16 + ln16) * 32 + k0];
      const float bk0 = p.cak_b[ln16], bk1 = p.cak_b[16 + ln16];
      const float bv0 = p.cav_b[ln16], bv1 = p.cav_b[16 + ln16];
      f32x4 K0 = {bk0,bk0,bk0,bk0}, K1 = {bk1,bk1,bk1,bk1};
      f32x4 V0 = {bv0,bv0,bv0,bv0}, V1 = {bv1,bv1,bv1,bv1};
      PRIO_HI();
      MFMA(K0, af, wk0); MFMA(K1, af, wk1); MFMA(V0, af, wv0); MFMA(V1, af, wv1);
      PRIO_LO();
#pragma unroll
      for (int r2 = 0; r2 < 4; ++r2) {
        const int row = kg * 4 + r2;
        s_ub[g][row * 32 + ln16] = f2b(K0[r2]);
        s_ub[g][row * 32 + 16 + ln16] = f2b(K1[r2]);
        s_ub[g][512 + row * 32 + ln16] = f2b(V0[r2]);
        s_ub[g][512 + row * 32 + 16 + ln16] = f2b(V1[r2]);
      }
    }
  }

  // ================= Phase D: both batches dual-streamed =================
  {
    const float* b2d = p.cap_b2;
    const float* bc1 = p.caa_b1;
    const float* bc2 = p.caa_b2;
    const float* fw1 = p.fw1; const float* fw2 = p.fw2; const float* fw3 = p.fw3;
    const float* cqw = p.caq_w;
    const float* iw1 = p.im_w1; const float* iw2 = p.im_w2; const float* iw3 = p.im_w3;
    const unsigned short* wsd = ws;
    for (int s = 0; s <= 8; ++s) {
      asm volatile("" : "+s"(b2d), "+s"(bc1), "+s"(bc2), "+s"(wsd));
      asm volatile("" : "+s"(fw1), "+s"(fw2), "+s"(fw3), "+s"(cqw), "+s"(iw1), "+s"(iw2), "+s"(iw3));
      float rv0 = 0.f, rv1 = 0.f, rv2 = 0.f;
      // rel: lanes 0-15 batch0, lanes 32-47 batch1
      if (s < 8 && lh < 16) {
        const int k = lh;
        const float r0 = s_coords[gH][k * 3 + 0] - s_op[gH][0];
        const float r1 = s_coords[gH][k * 3 + 1] - s_op[gH][1];
        const float r2 = s_coords[gH][k * 3 + 2] - s_op[gH][2];
        const float rd = sqrtf(r0 * r0 + r1 * r1 + r2 * r2);
        const float inv = 1.f / rd;
        rv0 = r0 * inv; rv1 = r1 * inv; rv2 = r2 * inv;
        s_reld[gH][k] = rd;
        s_relv[gH][k * 3 + 0] = rv0; s_relv[gH][k * 3 + 1] = rv1; s_relv[gH][k * 3 + 2] = rv2;
        p.o_ld[(b0 + gH) * 128 + s * 16 + k] = rd;
      }
      {  // secA dual: hv for both batches, 4-n-tile groups
        float c00, c01, c02, c10, c11, c12;
        if (s < 8) {
          c00 = s_coords[0][ln16 * 3 + 0] - s_op[0][0];
          c01 = s_coords[0][ln16 * 3 + 1] - s_op[0][1];
          c02 = s_coords[0][ln16 * 3 + 2] - s_op[0][2];
          c10 = s_coords[1][ln16 * 3 + 0] - s_op[1][0];
          c11 = s_coords[1][ln16 * 3 + 1] - s_op[1][1];
          c12 = s_coords[1][ln16 * 3 + 2] - s_op[1][2];
        } else {
          const float rd0 = s_reld[0][ln16], rd1 = s_reld[1][ln16];
          c00 = s_relv[0][ln16 * 3 + 0] * rd0; c01 = s_relv[0][ln16 * 3 + 1] * rd0;
          c02 = s_relv[0][ln16 * 3 + 2] * rd0;
          c10 = s_relv[1][ln16 * 3 + 0] * rd1; c11 = s_relv[1][ln16 * 3 + 1] * rd1;
          c12 = s_relv[1][ln16 * 3 + 2] * rd1;
        }
        union { s16x8 v; unsigned u[4]; } cv0, cv1;
        cv0.u[0] = (kg == 0) ? pack2(c00, c01) : 0u;
        cv0.u[1] = (kg == 0) ? pack2(c02, 1.0f) : 0u;
        cv0.u[2] = 0u; cv0.u[3] = 0u;
        cv1.u[0] = (kg == 0) ? pack2(c10, c11) : 0u;
        cv1.u[1] = (kg == 0) ? pack2(c12, 1.0f) : 0u;
        cv1.u[2] = 0u; cv1.u[3] = 0u;
        const s16x8 af0 = cv0.v, af1 = cv1.v;
#pragma unroll
        for (int g2b = 0; g2b < 2; ++g2b) {
          const int nbase = g2b * 4;
          const s16x8 w0 = *(const s16x8*)&wsd[WH_CAP + ((nbase + 0) * 16 + ln16) * 32 + k0];
          const s16x8 w1 = *(const s16x8*)&wsd[WH_CAP + ((nbase + 1) * 16 + ln16) * 32 + k0];
          const s16x8 w2 = *(const s16x8*)&wsd[WH_CAP + ((nbase + 2) * 16 + ln16) * 32 + k0];
          const s16x8 w3 = *(const s16x8*)&wsd[WH_CAP + ((nbase + 3) * 16 + ln16) * 32 + k0];
          f32x4 A00 = {0.f,0.f,0.f,0.f}, A01 = {0.f,0.f,0.f,0.f};
          f32x4 A02 = {0.f,0.f,0.f,0.f}, A03 = {0.f,0.f,0.f,0.f};
          f32x4 A10 = {0.f,0.f,0.f,0.f}, A11 = {0.f,0.f,0.f,0.f};
          f32x4 A12 = {0.f,0.f,0.f,0.f}, A13 = {0.f,0.f,0.f,0.f};
          PRIO_HI();
          MFMA(A00, af0, w0); MFMA(A10, af1, w0);
          MFMA(A01, af0, w1); MFMA(A11, af1, w1);
          MFMA(A02, af0, w2); MFMA(A12, af1, w2);
          MFMA(A03, af0, w3); MFMA(A13, af1, w3);
          PRIO_LO();
#pragma unroll
          for (int r2 = 0; r2 < 4; ++r2) {
            const int row = (kg * 4 + r2) * HSTR;
            s_workA[row + (nbase + 0) * 16 + ln16] = f2b(fmaxf(A00[r2], 0.f));
            s_workA[row + (nbase + 1) * 16 + ln16] = f2b(fmaxf(A01[r2], 0.f));
            s_workA[row + (nbase + 2) * 16 + ln16] = f2b(fmaxf(A02[r2], 0.f));
            s_workA[row + (nbase + 3) * 16 + ln16] = f2b(fmaxf(A03[r2], 0.f));
            s_workB[row + (nbase + 0) * 16 + ln16] = f2b(fmaxf(A10[r2], 0.f));
            s_workB[row + (nbase + 1) * 16 + ln16] = f2b(fmaxf(A11[r2], 0.f));
            s_workB[row + (nbase + 2) * 16 + ln16] = f2b(fmaxf(A12[r2], 0.f));
            s_workB[row + (nbase + 3) * 16 + ln16] = f2b(fmaxf(A13[r2], 0.f));
          }
        }
      }
      {  // qq chain: half gH computes its batch (width-32 shuffles in-half)
        const int h = lh;
        float opc0, opc1, opc2;
        if (s < 8) {
          const float cum = s_cum[gH];
          opc0 = s_qry[gH][0] * cum; opc1 = s_qry[gH][1] * cum; opc2 = s_qry[gH][2] * cum;
        } else {
          opc0 = s_op[gH][0]; opc1 = s_op[gH][1]; opc2 = s_op[gH][2];
        }
        float v1 = fmaxf(fmaf(opc0, fw1[h],
                      fmaf(opc1, fw1[32 + h],
                      fmaf(opc2, fw1[64 + h], p.fb1[h]))), 0.f);
        float a = p.fb2[h];
        for (int i2 = 0; i2 < 32; ++i2) a = fmaf(__shfl(v1, i2, 32), fw2[i2 * 32 + h], a);
        const float v2 = fmaxf(a, 0.f);
        a = p.fb3[h];
        for (int i2 = 0; i2 < 32; ++i2) a = fmaf(__shfl(v2, i2, 32), fw3[i2 * 32 + h], a);
        const float opf = a;
        a = p.caq_b[h];
        for (int i2 = 0; i2 < 32; ++i2) a = fmaf(__shfl(opf, i2, 32), cqw[i2 * 32 + h], a);
        s_qq[gH][h] = a;
      }
      f32x4 pe00, pe01, pe10, pe11;
      {  // secB dual: batched B, staggered A pairs
#pragma unroll
        for (int nb = 0; nb < 2; ++nb) {
          const int n = nb * 16 + ln16;
          const s16x8 w0 = *(const s16x8*)&wsd[WA_CAP + n * 128 + 0 * 32 + k0];
          const s16x8 w1 = *(const s16x8*)&wsd[WA_CAP + n * 128 + 1 * 32 + k0];
          const s16x8 w2 = *(const s16x8*)&wsd[WA_CAP + n * 128 + 2 * 32 + k0];
          const s16x8 w3 = *(const s16x8*)&wsd[WA_CAP + n * 128 + 3 * 32 + k0];
          const float bias = b2d[n];
          f32x4 acc0 = {bias, bias, bias, bias};
          f32x4 acc1 = {bias, bias, bias, bias};
          PRIO_HI();
          {
            const s16x8 a0 = *(const s16x8*)&s_workA[ln16 * HSTR + 0 * 32 + k0];
            const s16x8 a1 = *(const s16x8*)&s_workB[ln16 * HSTR + 0 * 32 + k0];
            MFMA(acc0, a0, w0); MFMA(acc1, a1, w0);
          }
          {
            const s16x8 a0 = *(const s16x8*)&s_workA[ln16 * HSTR + 1 * 32 + k0];
            const s16x8 a1 = *(const s16x8*)&s_workB[ln16 * HSTR + 1 * 32 + k0];
            MFMA(acc0, a0, w1); MFMA(acc1, a1, w1);
          }
          {
            const s16x8 a0 = *(const s16x8*)&s_workA[ln16 * HSTR + 2 * 32 + k0];
            const s16x8 a1 = *(const s16x8*)&s_workB[ln16 * HSTR + 2 * 32 + k0];
            MFMA(acc0, a0, w2); MFMA(acc1, a1, w2);
          }
          {
            const s16x8 a0 = *(const s16x8*)&s_workA[ln16 * HSTR + 3 * 32 + k0];
            const s16x8 a1 = *(const s16x8*)&s_workB[ln16 * HSTR + 3 * 32 + k0];
            MFMA(acc0, a0, w3); MFMA(acc1, a1, w3);
          }
          PRIO_LO();
          if (nb == 0) { pe00 = acc0; pe10 = acc1; }
          else { pe01 = acc0; pe11 = acc1; }
#pragma unroll
          for (int r2 = 0; r2 < 4; ++r2) {
            const int row = kg * 4 + r2;
            s_simbA[row * BSTR + n] =
              f2b(s_qq[0][n] - b2f(s_ub[0][row * 32 + n]) + acc0[r2]);
            s_simbB[row * BSTR + n] =
              f2b(s_qq[1][n] - b2f(s_ub[1][row * 32 + n]) + acc1[r2]);
          }
        }
      }
      {  // secC dual: 4-n-tile groups
        const s16x8 as0 = *(const s16x8*)&s_simbA[ln16 * BSTR + k0];
        const s16x8 as1 = *(const s16x8*)&s_simbB[ln16 * BSTR + k0];
#pragma unroll
        for (int g2b = 0; g2b < 2; ++g2b) {
          const int nbase = g2b * 4;
          const s16x8 w0 = *(const s16x8*)&wsd[WB_CAA + ((nbase + 0) * 16 + ln16) * 32 + k0];
          const s16x8 w1 = *(const s16x8*)&wsd[WB_CAA + ((nbase + 1) * 16 + ln16) * 32 + k0];
          const s16x8 w2 = *(const s16x8*)&wsd[WB_CAA + ((nbase + 2) * 16 + ln16) * 32 + k0];
          const s16x8 w3 = *(const s16x8*)&wsd[WB_CAA + ((nbase + 3) * 16 + ln16) * 32 + k0];
          const float b0v = bc1[(nbase + 0) * 16 + ln16];
          const float b1v = bc1[(nbase + 1) * 16 + ln16];
          const float b2v = bc1[(nbase + 2) * 16 + ln16];
          const float b3v = bc1[(nbase + 3) * 16 + ln16];
          f32x4 A00 = {b0v,b0v,b0v,b0v}, A01 = {b1v,b1v,b1v,b1v};
          f32x4 A02 = {b2v,b2v,b2v,b2v}, A03 = {b3v,b3v,b3v,b3v};
          f32x4 A10 = {b0v,b0v,b0v,b0v}, A11 = {b1v,b1v,b1v,b1v};
          f32x4 A12 = {b2v,b2v,b2v,b2v}, A13 = {b3v,b3v,b3v,b3v};
          PRIO_HI();
          MFMA(A00, as0, w0); MFMA(A10, as1, w0);
          MFMA(A01, as0, w1); MFMA(A11, as1, w1);
          MFMA(A02, as0, w2); MFMA(A12, as1, w2);
          MFMA(A03, as0, w3); MFMA(A13, as1, w3);
          PRIO_LO();
#pragma unroll
          for (int r2 = 0; r2 < 4; ++r2) {
            const int row = (kg * 4 + r2) * HSTR;
            s_workA[row + (nbase + 0) * 16 + ln16] = f2b(fmaxf(A00[r2], 0.f));
            s_workA[row + (nbase + 1) * 16 + ln16] = f2b(fmaxf(A01[r2], 0.f));
            s_workA[row + (nbase + 2) * 16 + ln16] = f2b(fmaxf(A02[r2], 0.f));
            s_workA[row + (nbase + 3) * 16 + ln16] = f2b(fmaxf(A03[r2], 0.f));
            s_workB[row + (nbase + 0) * 16 + ln16] = f2b(fmaxf(A10[r2], 0.f));
            s_workB[row + (nbase + 1) * 16 + ln16] = f2b(fmaxf(A11[r2], 0.f));
            s_workB[row + (nbase + 2) * 16 + ln16] = f2b(fmaxf(A12[r2], 0.f));
            s_workB[row + (nbase + 3) * 16 + ln16] = f2b(fmaxf(A13[r2], 0.f));
          }
        }
      }
      {  // secD dual + softmax -> s_ca[g] (batched B, staggered h pairs)
#pragma unroll
        for (int nb = 0; nb < 2; ++nb) {
          const int n = nb * 16 + ln16;
          const s16x8 w0 = *(const s16x8*)&wsd[WC_CAA + n * 128 + 0 * 32 + k0];
          const s16x8 w1 = *(const s16x8*)&wsd[WC_CAA + n * 128 + 1 * 32 + k0];
          const s16x8 w2 = *(const s16x8*)&wsd[WC_CAA + n * 128 + 2 * 32 + k0];
          const s16x8 w3 = *(const s16x8*)&wsd[WC_CAA + n * 128 + 3 * 32 + k0];
          const float bias = bc2[n];
          f32x4 acc0 = {bias, bias, bias, bias};
          f32x4 acc1 = {bias, bias, bias, bias};
          PRIO_HI();
          {
            const s16x8 h0 = *(const s16x8*)&s_workA[ln16 * HSTR + 0 * 32 + k0];
            const s16x8 h1 = *(const s16x8*)&s_workB[ln16 * HSTR + 0 * 32 + k0];
            MFMA(acc0, h0, w0); MFMA(acc1, h1, w0);
          }
          {
            const s16x8 h0 = *(const s16x8*)&s_workA[ln16 * HSTR + 1 * 32 + k0];
            const s16x8 h1 = *(const s16x8*)&s_workB[ln16 * HSTR + 1 * 32 + k0];
            MFMA(acc0, h0, w1); MFMA(acc1, h1, w1);
          }
          {
            const s16x8 h0 = *(const s16x8*)&s_workA[ln16 * HSTR + 2 * 32 + k0];
            const s16x8 h1 = *(const s16x8*)&s_workB[ln16 * HSTR + 2 * 32 + k0];
            MFMA(acc0, h0, w2); MFMA(acc1, h1, w2);
          }
          {
            const s16x8 h0 = *(const s16x8*)&s_workA[ln16 * HSTR + 3 * 32 + k0];
            const s16x8 h1 = *(const s16x8*)&s_workB[ln16 * HSTR + 3 * 32 + k0];
            MFMA(acc0, h0, w3); MFMA(acc1, h1, w3);
          }
          PRIO_LO();
          const f32x4 rp0 = nb ? pe01 : pe00;
          const f32x4 rp1 = nb ? pe11 : pe10;
          float mx = fmaxf(fmaxf(acc0[0], acc0[1]), fmaxf(acc0[2], acc0[3]));
          mx = fmaxf(mx, __shfl_xor(mx, 16));
          mx = fmaxf(mx, __shfl_xor(mx, 32));
          float sum = 0.f, o = 0.f;
#pragma unroll
          for (int r2 = 0; r2 < 4; ++r2) {
            const int row = kg * 4 + r2;
            const float e = __expf(acc0[r2] - mx);
            sum += e;
            o = fmaf(e, b2f(s_ub[0][512 + row * 32 + n]) + rp0[r2], o);
          }
          sum += __shfl_xor(sum, 16); o += __shfl_xor(o, 16);
          sum += __shfl_xor(sum, 32); o += __shfl_xor(o, 32);
          if (kg == 0) s_ca[0][n] = o / sum;
          float mx1 = fmaxf(fmaxf(acc1[0], acc1[1]), fmaxf(acc1[2], acc1[3]));
          mx1 = fmaxf(mx1, __shfl_xor(mx1, 16));
          mx1 = fmaxf(mx1, __shfl_xor(mx1, 32));
          float sum1 = 0.f, o1 = 0.f;
#pragma unroll
          for (int r2 = 0; r2 < 4; ++r2) {
            const int row = kg * 4 + r2;
            const float e = __expf(acc1[r2] - mx1);
            sum1 += e;
            o1 = fmaf(e, b2f(s_ub[1][512 + row * 32 + n]) + rp1[r2], o1);
          }
          sum1 += __shfl_xor(sum1, 16); o1 += __shfl_xor(o1, 16);
          sum1 += __shfl_xor(sum1, 32); o1 += __shfl_xor(o1, 32);
          if (kg == 0) s_ca[1][n] = o1 / sum1;
        }
      }
      {  // im / ep chain: half gH = its batch; width-32 shuffles in-half
        const int h = lh;
        const int bD = b0 + gH;
        const float cav = s_ca[gH][h];
        if (s < 8) {
          float a = p.im_b1[h];
          for (int i2 = 0; i2 < 32; ++i2) a = fmaf(__shfl(cav, i2, 32), iw1[i2 * 32 + h], a);
          const float m1 = fmaxf(a, 0.f);
          a = p.im_b2[h];
          for (int i2 = 0; i2 < 32; ++i2) a = fmaf(__shfl(m1, i2, 32), iw2[i2 * 32 + h], a);
          const float m2 = fmaxf(a, 0.f);
          float p0 = m2 * iw3[h * 3 + 0];
          float p1 = m2 * iw3[h * 3 + 1];
          float p2 = m2 * iw3[h * 3 + 2];
#pragma unroll
          for (int m = 1; m < 32; m <<= 1) {
            p0 += __shfl_xor(p0, m, 32);
            p1 += __shfl_xor(p1, m, 32);
            p2 += __shfl_xor(p2, m, 32);
          }
          p0 += p.im_b3[0]; p1 += p.im_b3[1]; p2 += p.im_b3[2];
          const float step = sqrtf(p0 * p0 + p1 * p1 + p2 * p2);
          const float cum = s_cum[gH];
          const float opc0 = s_qry[gH][0] * cum;
          const float opc1 = s_qry[gH][1] * cum;
          const float opc2 = s_qry[gH][2] * cum;
          const float inv = 1.f / step;
          const float tg0 = p0 * inv, tg1 = p1 * inv, tg2 = p2 * inv;
          if (lh == 0) {
            p.o_ms[bD * 8 + s] = step;
            p.o_ip[(bD * 8 + s) * 3 + 0] = opc0 + p0;
            s_op[gH][0] = opc0 + s_qry[gH][0] * step;
          } else if (lh == 1) {
            p.o_ip[(bD * 8 + s) * 3 + 1] = opc1 + p1;
            s_op[gH][1] = opc1 + s_qry[gH][1] * step;
          } else if (lh == 2) {
            p.o_ip[(bD * 8 + s) * 3 + 2] = opc2 + p2;
            s_op[gH][2] = opc2 + s_qry[gH][2] * step;
          } else if (lh == 3) {
            s_cum[gH] = cum + step;
          }
          if (lh < 16) {
            p.o_cs[bD * 128 + s * 16 + lh] = tg0 * rv0 + tg1 * rv1 + tg2 * rv2;
          }
        } else {
          float a = p.ep_b1[h];
          for (int i2 = 0; i2 < 32; ++i2) a = fmaf(__shfl(cav, i2, 32), p.ep_w1[i2 * 32 + h], a);
          a = fmaf(s_qry[gH][0], p.ep_w1[1024 + h], a);
          a = fmaf(s_qry[gH][1], p.ep_w1[1056 + h], a);
          a = fmaf(s_qry[gH][2], p.ep_w1[1088 + h], a);
          const float e1 = fmaxf(a, 0.f);
          a = p.ep_b2[h];
          for (int i2 = 0; i2 < 32; ++i2) a = fmaf(__shfl(e1, i2, 32), p.ep_w2[i2 * 32 + h], a);
          const float e2 = fmaxf(a, 0.f);
          float pp = e2 * p.ep_w3[h];
#pragma unroll
          for (int m = 1; m < 32; m <<= 1) pp += __shfl_xor(pp, m, 32);
          if (lh == 0) {
            p.o_eps[bD] = pp + p.ep_b3[0];
            p.o_cum[bD] = s_cum[gH];
          }
        }
      }
    }
  }
}

extern "C" void kernel_launch(void* const* d_in, const int* in_sizes, int n_in,
                              void* d_out, int out_size, void* d_ws, size_t ws_size,
                              hipStream_t stream) {
  Params p;
  const float** f = (const float**)(void*)&p;
  for (int i = 0; i < 43; ++i) f[i] = (const float*)d_in[i];
  float* out = (float*)d_out;
  p.o_ld  = out;
  p.o_ms  = out + OFF_MS;
  p.o_cs  = out + OFF_CS;
  p.o_ip  = out + OFF_IP;
  p.o_cum = out + OFF_CUM;
  p.o_eps = out + OFF_EPS;
  unsigned short* ws = (unsigned short*)d_ws;
  prep_kernel<<<dim3(16), dim3(256), 0, stream>>>(p, ws);
  puray_kernel<<<dim3(2048), dim3(64), 0, stream>>>(p, ws);
}

// Round 30
// 227.760 us; speedup vs baseline: 1.5871x; 1.5871x over previous
//
#include <hip/hip_runtime.h>

// Problem constants: B=4096, K=16, H=32, HM=128, STEPS=8
#define OFF_MS  524288
#define OFF_CS  557056
#define OFF_IP  1081344
#define OFF_CUM 1179648
#define OFF_EPS 1183744

#define HSTR 136
#define BSTR 40

// d_ws layout (u16): bf16 weights transposed to [n][k]
#define WA_PTP 0
#define WB_PTA 4096
#define WC_PTA 8192
#define WA_CAP 12288
#define WB_CAA 16384
#define WC_CAA 20480
#define WH_PTP 24576
#define WH_CAP 28672
#define WF1    32768
#define WF2    33792
#define WF3    34816
#define WQKV   35840
#define WKK    38912
#define WVV    39936

struct Params {
  const float *knn, *query, *fw1, *fb1, *fw2, *fb2, *fw3, *fb3, *qkv_w,
    *ptp_w1, *ptp_b1, *ptp_w2, *ptp_b2, *pta_w1, *pta_b1, *pta_w2, *pta_b2,
    *caq_w, *caq_b, *cak_w, *cak_b, *cav_w, *cav_b,
    *cap_w1, *cap_b1, *cap_w2, *cap_b2, *caa_w1, *caa_b1, *caa_w2, *caa_b2,
    *im_w1, *im_b1, *im_w2, *im_b2, *im_w3, *im_b3,
    *ep_w1, *ep_b1, *ep_w2, *ep_b2, *ep_w3, *ep_b3;
  float *o_ld, *o_ms, *o_cs, *o_ip, *o_cum, *o_eps;
};
static_assert(sizeof(Params) == 49 * sizeof(void*), "Params layout");

typedef float f32x4 __attribute__((ext_vector_type(4)));
typedef short s16x8 __attribute__((ext_vector_type(8)));

__device__ __forceinline__ unsigned short f2b(float x) {
  unsigned u = __float_as_uint(x);
  u += 0x7fffu + ((u >> 16) & 1u);
  return (unsigned short)(u >> 16);
}
__device__ __forceinline__ float b2f(unsigned short x) {
  return __uint_as_float((unsigned)x << 16);
}
__device__ __forceinline__ unsigned pack2(float lo, float hi) {
  return (unsigned)f2b(lo) | ((unsigned)f2b(hi) << 16);
}

#define MFMA(acc, a, bb) \
  (acc = __builtin_amdgcn_mfma_f32_16x16x32_bf16((a), (bb), (acc), 0, 0, 0))
#define PRIO_HI() __builtin_amdgcn_s_setprio(1)
#define PRIO_LO() __builtin_amdgcn_s_setprio(0)

__global__ void prep_kernel(Params p, unsigned short* ws) {
  const int t = blockIdx.x * 256 + threadIdx.x;
  const int n = t >> 7, k = t & 127;
  ws[WA_PTP + t] = f2b(p.ptp_w2[k * 32 + n]);
  ws[WC_PTA + t] = f2b(p.pta_w2[k * 32 + n]);
  ws[WA_CAP + t] = f2b(p.cap_w2[k * 32 + n]);
  ws[WC_CAA + t] = f2b(p.caa_w2[k * 32 + n]);
  const int n2 = t >> 5, k2 = t & 31;
  ws[WB_PTA + t] = f2b(p.pta_w1[k2 * 128 + n2]);
  ws[WB_CAA + t] = f2b(p.caa_w1[k2 * 128 + n2]);
  ws[WH_PTP + t] = (k2 < 3) ? f2b(p.ptp_w1[k2 * 128 + n2])
                  : (k2 == 3 ? f2b(p.ptp_b1[n2]) : (unsigned short)0);
  ws[WH_CAP + t] = (k2 < 3) ? f2b(p.cap_w1[k2 * 128 + n2])
                  : (k2 == 3 ? f2b(p.cap_b1[n2]) : (unsigned short)0);
  if (t < 1024) {
    ws[WF1 + t] = (k2 < 3) ? f2b(p.fw1[k2 * 32 + n2])
                 : (k2 == 3 ? f2b(p.fb1[n2]) : (unsigned short)0);
    ws[WF2 + t] = f2b(p.fw2[k2 * 32 + n2]);
    ws[WF3 + t] = f2b(p.fw3[k2 * 32 + n2]);
    ws[WKK + t] = f2b(p.cak_w[k2 * 32 + n2]);
    ws[WVV + t] = f2b(p.cav_w[k2 * 32 + n2]);
  }
  if (t < 3072) ws[WQKV + t] = f2b(p.qkv_w[k2 * 96 + n2]);
}

// FINAL (revert to round 28, 228.0us): builtin MFMA + s_setprio(T5) +
// __launch_bounds__(64,2). Round 29 proved the 128-VGPR cap is mandatory:
// VGPR 148 under (64,1) crossed the 128 wave-slot quantum -> occupancy
// 22.7->11.7% (2->1 wave/SIMD), dur 361us. The ~14MB residual spill under
// the cap costs <7us; a lost wave slot costs ~130us.
__launch_bounds__(64, 2)
__global__ void puray_kernel(Params p, const unsigned short* ws) {
  const int b0 = blockIdx.x * 2;
  const int l = threadIdx.x;
  const int ln16 = l & 15, kg = l >> 4, k0 = kg * 8;
  const int gH = l >> 5, lh = l & 31;   // half id = batch for scalar parts

  __shared__ __align__(16) unsigned short s_workA[16 * HSTR];
  __shared__ __align__(16) unsigned short s_workB[16 * HSTR];
  __shared__ __align__(16) unsigned short s_simbA[16 * BSTR];
  __shared__ __align__(16) unsigned short s_simbB[16 * BSTR];
  __shared__ __align__(16) unsigned short s_featb[2][16 * BSTR];
  __shared__ __align__(16) unsigned short s_ub[2][1024];  // bf16 q|k / kk|vv
  __shared__ __align__(16) unsigned short s_vb[512];      // bf16 v (per-batch C)
  __shared__ float s_coords[2][48], s_relv[2][48], s_reld[2][16];
  __shared__ float s_qry[2][3], s_op[2][3], s_qq[2][32], s_ca[2][32];
  __shared__ float s_cum[2];

  for (int idx = l; idx < 96; idx += 64) s_coords[idx / 48][idx % 48] = p.knn[b0 * 48 + idx];
  if (l < 6) s_qry[l / 3][l % 3] = p.query[b0 * 3 + l];
  else if (l < 8) s_cum[l - 6] = 0.f;
  else if (l < 14) s_op[(l - 8) / 3][(l - 8) % 3] = 0.f;
  __syncthreads();

  // ================= Phases A/B/C + kkvv per batch =================
  for (int g = 0; g < 2; ++g) {
    const float* cg = s_coords[g];
    {  // A-L1: coords -> h1 (s_simbA)
      union { s16x8 v; unsigned u[4]; } cv;
      cv.u[0] = (kg == 0) ? pack2(cg[ln16 * 3 + 0], cg[ln16 * 3 + 1]) : 0u;
      cv.u[1] = (kg == 0) ? pack2(cg[ln16 * 3 + 2], 1.0f) : 0u;
      cv.u[2] = 0u; cv.u[3] = 0u;
      const s16x8 af = cv.v;
      const s16x8 w0 = *(const s16x8*)&ws[WF1 + (0 * 16 + ln16) * 32 + k0];
      const s16x8 w1 = *(const s16x8*)&ws[WF1 + (1 * 16 + ln16) * 32 + k0];
      f32x4 A0 = {0.f,0.f,0.f,0.f}, A1 = {0.f,0.f,0.f,0.f};
      PRIO_HI();
      MFMA(A0, af, w0); MFMA(A1, af, w1);
      PRIO_LO();
#pragma unroll
      for (int r2 = 0; r2 < 4; ++r2) {
        const int row = (kg * 4 + r2) * BSTR;
        s_simbA[row + 0 * 16 + ln16] = f2b(fmaxf(A0[r2], 0.f));
        s_simbA[row + 1 * 16 + ln16] = f2b(fmaxf(A1[r2], 0.f));
      }
    }
    {  // A-L2: h1 -> h2 (s_workA)
      const s16x8 af = *(const s16x8*)&s_simbA[ln16 * BSTR + k0];
      const s16x8 w0 = *(const s16x8*)&ws[WF2 + (0 * 16 + ln16) * 32 + k0];
      const s16x8 w1 = *(const s16x8*)&ws[WF2 + (1 * 16 + ln16) * 32 + k0];
      const float b0v = p.fb2[ln16], b1v = p.fb2[16 + ln16];
      f32x4 A0 = {b0v,b0v,b0v,b0v}, A1 = {b1v,b1v,b1v,b1v};
      PRIO_HI();
      MFMA(A0, af, w0); MFMA(A1, af, w1);
      PRIO_LO();
#pragma unroll
      for (int r2 = 0; r2 < 4; ++r2) {
        const int row = (kg * 4 + r2) * HSTR;
        s_workA[row + 0 * 16 + ln16] = f2b(fmaxf(A0[r2], 0.f));
        s_workA[row + 1 * 16 + ln16] = f2b(fmaxf(A1[r2], 0.f));
      }
    }
    {  // A-L3: h2 -> feats (s_featb[g])
      const s16x8 af = *(const s16x8*)&s_workA[ln16 * HSTR + k0];
      const s16x8 w0 = *(const s16x8*)&ws[WF3 + (0 * 16 + ln16) * 32 + k0];
      const s16x8 w1 = *(const s16x8*)&ws[WF3 + (1 * 16 + ln16) * 32 + k0];
      const float b0v = p.fb3[ln16], b1v = p.fb3[16 + ln16];
      f32x4 A0 = {b0v,b0v,b0v,b0v}, A1 = {b1v,b1v,b1v,b1v};
      PRIO_HI();
      MFMA(A0, af, w0); MFMA(A1, af, w1);
      PRIO_LO();
#pragma unroll
      for (int r2 = 0; r2 < 4; ++r2) {
        const int row = (kg * 4 + r2) * BSTR;
        s_featb[g][row + 0 * 16 + ln16] = f2b(A0[r2]);
        s_featb[g][row + 1 * 16 + ln16] = f2b(A1[r2]);
      }
    }
    {  // B: qkv -> s_ub[g] (q|k, bf16) + s_vb (bf16)
      const s16x8 af = *(const s16x8*)&s_featb[g][ln16 * BSTR + k0];
#pragma unroll
      for (int g6 = 0; g6 < 2; ++g6) {
        const int nb0 = g6 * 3;
        const s16x8 w0 = *(const s16x8*)&ws[WQKV + ((nb0 + 0) * 16 + ln16) * 32 + k0];
        const s16x8 w1 = *(const s16x8*)&ws[WQKV + ((nb0 + 1) * 16 + ln16) * 32 + k0];
        const s16x8 w2 = *(const s16x8*)&ws[WQKV + ((nb0 + 2) * 16 + ln16) * 32 + k0];
        f32x4 A0 = {0.f,0.f,0.f,0.f}, A1 = {0.f,0.f,0.f,0.f}, A2 = {0.f,0.f,0.f,0.f};
        PRIO_HI();
        MFMA(A0, af, w0); MFMA(A1, af, w1); MFMA(A2, af, w2);
        PRIO_LO();
#pragma unroll
        for (int j6 = 0; j6 < 3; ++j6) {
          const int o = (nb0 + j6) * 16 + ln16;
          const f32x4 acc = (j6 == 0) ? A0 : (j6 == 1) ? A1 : A2;
#pragma unroll
          for (int r2 = 0; r2 < 4; ++r2) {
            const int row = kg * 4 + r2;
            if (o < 32) s_ub[g][row * 32 + o] = f2b(acc[r2]);
            else if (o < 64) s_ub[g][512 + row * 32 + o - 32] = f2b(acc[r2]);
            else s_vb[row * 32 + o - 64] = f2b(acc[r2]);
          }
        }
      }
    }
    // ---- Phase C (dual-i streams within batch g) ----
    {
      const float* b2c = p.ptp_b2;
      const float* bh1 = p.pta_b1;
      const float* bh2 = p.pta_b2;
      const unsigned short* wsc = ws;
      for (int ip = 0; ip < 8; ++ip) {
        asm volatile("" : "+s"(b2c), "+s"(bh1), "+s"(bh2), "+s"(wsc));
        const int i0 = ip * 2, i1 = ip * 2 + 1;
        const float c00 = cg[i0 * 3 + 0] - cg[ln16 * 3 + 0];
        const float c01 = cg[i0 * 3 + 1] - cg[ln16 * 3 + 1];
        const float c02 = cg[i0 * 3 + 2] - cg[ln16 * 3 + 2];
        const float c10 = cg[i1 * 3 + 0] - cg[ln16 * 3 + 0];
        const float c11 = cg[i1 * 3 + 1] - cg[ln16 * 3 + 1];
        const float c12 = cg[i1 * 3 + 2] - cg[ln16 * 3 + 2];
        {  // hv dual: 4-n-tile groups
          union { s16x8 v; unsigned u[4]; } cv0, cv1;
          cv0.u[0] = (kg == 0) ? pack2(c00, c01) : 0u;
          cv0.u[1] = (kg == 0) ? pack2(c02, 1.0f) : 0u;
          cv0.u[2] = 0u; cv0.u[3] = 0u;
          cv1.u[0] = (kg == 0) ? pack2(c10, c11) : 0u;
          cv1.u[1] = (kg == 0) ? pack2(c12, 1.0f) : 0u;
          cv1.u[2] = 0u; cv1.u[3] = 0u;
          const s16x8 af0 = cv0.v, af1 = cv1.v;
#pragma unroll
          for (int g2b = 0; g2b < 2; ++g2b) {
            const int nbase = g2b * 4;
            const s16x8 w0 = *(const s16x8*)&wsc[WH_PTP + ((nbase + 0) * 16 + ln16) * 32 + k0];
            const s16x8 w1 = *(const s16x8*)&wsc[WH_PTP + ((nbase + 1) * 16 + ln16) * 32 + k0];
            const s16x8 w2 = *(const s16x8*)&wsc[WH_PTP + ((nbase + 2) * 16 + ln16) * 32 + k0];
            const s16x8 w3 = *(const s16x8*)&wsc[WH_PTP + ((nbase + 3) * 16 + ln16) * 32 + k0];
            f32x4 A00 = {0.f,0.f,0.f,0.f}, A01 = {0.f,0.f,0.f,0.f};
            f32x4 A02 = {0.f,0.f,0.f,0.f}, A03 = {0.f,0.f,0.f,0.f};
            f32x4 A10 = {0.f,0.f,0.f,0.f}, A11 = {0.f,0.f,0.f,0.f};
            f32x4 A12 = {0.f,0.f,0.f,0.f}, A13 = {0.f,0.f,0.f,0.f};
            PRIO_HI();
            MFMA(A00, af0, w0); MFMA(A10, af1, w0);
            MFMA(A01, af0, w1); MFMA(A11, af1, w1);
            MFMA(A02, af0, w2); MFMA(A12, af1, w2);
            MFMA(A03, af0, w3); MFMA(A13, af1, w3);
            PRIO_LO();
#pragma unroll
            for (int r2 = 0; r2 < 4; ++r2) {
              const int row = (kg * 4 + r2) * HSTR;
              s_workA[row + (nbase + 0) * 16 + ln16] = f2b(fmaxf(A00[r2], 0.f));
              s_workA[row + (nbase + 1) * 16 + ln16] = f2b(fmaxf(A01[r2], 0.f));
              s_workA[row + (nbase + 2) * 16 + ln16] = f2b(fmaxf(A02[r2], 0.f));
              s_workA[row + (nbase + 3) * 16 + ln16] = f2b(fmaxf(A03[r2], 0.f));
              s_workB[row + (nbase + 0) * 16 + ln16] = f2b(fmaxf(A10[r2], 0.f));
              s_workB[row + (nbase + 1) * 16 + ln16] = f2b(fmaxf(A11[r2], 0.f));
              s_workB[row + (nbase + 2) * 16 + ln16] = f2b(fmaxf(A12[r2], 0.f));
              s_workB[row + (nbase + 3) * 16 + ln16] = f2b(fmaxf(A13[r2], 0.f));
            }
          }
        }
        f32x4 rpe00, rpe01, rpe10, rpe11;
        {  // G1 dual: batched B, staggered A pairs
#pragma unroll
          for (int nb = 0; nb < 2; ++nb) {
            const int n = nb * 16 + ln16;
            const s16x8 w0 = *(const s16x8*)&wsc[WA_PTP + n * 128 + 0 * 32 + k0];
            const s16x8 w1 = *(const s16x8*)&wsc[WA_PTP + n * 128 + 1 * 32 + k0];
            const s16x8 w2 = *(const s16x8*)&wsc[WA_PTP + n * 128 + 2 * 32 + k0];
            const s16x8 w3 = *(const s16x8*)&wsc[WA_PTP + n * 128 + 3 * 32 + k0];
            const float bias = b2c[n];
            f32x4 acc0 = {bias, bias, bias, bias};
            f32x4 acc1 = {bias, bias, bias, bias};
            PRIO_HI();
            {
              const s16x8 a0 = *(const s16x8*)&s_workA[ln16 * HSTR + 0 * 32 + k0];
              const s16x8 a1 = *(const s16x8*)&s_workB[ln16 * HSTR + 0 * 32 + k0];
              MFMA(acc0, a0, w0); MFMA(acc1, a1, w0);
            }
            {
              const s16x8 a0 = *(const s16x8*)&s_workA[ln16 * HSTR + 1 * 32 + k0];
              const s16x8 a1 = *(const s16x8*)&s_workB[ln16 * HSTR + 1 * 32 + k0];
              MFMA(acc0, a0, w1); MFMA(acc1, a1, w1);
            }
            {
              const s16x8 a0 = *(const s16x8*)&s_workA[ln16 * HSTR + 2 * 32 + k0];
              const s16x8 a1 = *(const s16x8*)&s_workB[ln16 * HSTR + 2 * 32 + k0];
              MFMA(acc0, a0, w2); MFMA(acc1, a1, w2);
            }
            {
              const s16x8 a0 = *(const s16x8*)&s_workA[ln16 * HSTR + 3 * 32 + k0];
              const s16x8 a1 = *(const s16x8*)&s_workB[ln16 * HSTR + 3 * 32 + k0];
              MFMA(acc0, a0, w3); MFMA(acc1, a1, w3);
            }
            PRIO_LO();
            if (nb == 0) { rpe00 = acc0; rpe10 = acc1; }
            else { rpe01 = acc0; rpe11 = acc1; }
#pragma unroll
            for (int r2 = 0; r2 < 4; ++r2) {
              const int j = kg * 4 + r2;
              s_simbA[j * BSTR + n] =
                f2b(b2f(s_ub[g][i0 * 32 + n]) - b2f(s_ub[g][512 + j * 32 + n]) + acc0[r2]);
              s_simbB[j * BSTR + n] =
                f2b(b2f(s_ub[g][i1 * 32 + n]) - b2f(s_ub[g][512 + j * 32 + n]) + acc1[r2]);
            }
          }
        }
        {  // G2 dual: 4-n-tile groups
          const s16x8 as0 = *(const s16x8*)&s_simbA[ln16 * BSTR + k0];
          const s16x8 as1 = *(const s16x8*)&s_simbB[ln16 * BSTR + k0];
#pragma unroll
          for (int g2b = 0; g2b < 2; ++g2b) {
            const int nbase = g2b * 4;
            const s16x8 w0 = *(const s16x8*)&wsc[WB_PTA + ((nbase + 0) * 16 + ln16) * 32 + k0];
            const s16x8 w1 = *(const s16x8*)&wsc[WB_PTA + ((nbase + 1) * 16 + ln16) * 32 + k0];
            const s16x8 w2 = *(const s16x8*)&wsc[WB_PTA + ((nbase + 2) * 16 + ln16) * 32 + k0];
            const s16x8 w3 = *(const s16x8*)&wsc[WB_PTA + ((nbase + 3) * 16 + ln16) * 32 + k0];
            const float b0v = bh1[(nbase + 0) * 16 + ln16];
            const float b1v = bh1[(nbase + 1) * 16 + ln16];
            const float b2v = bh1[(nbase + 2) * 16 + ln16];
            const float b3v = bh1[(nbase + 3) * 16 + ln16];
            f32x4 A00 = {b0v,b0v,b0v,b0v}, A01 = {b1v,b1v,b1v,b1v};
            f32x4 A02 = {b2v,b2v,b2v,b2v}, A03 = {b3v,b3v,b3v,b3v};
            f32x4 A10 = {b0v,b0v,b0v,b0v}, A11 = {b1v,b1v,b1v,b1v};
            f32x4 A12 = {b2v,b2v,b2v,b2v}, A13 = {b3v,b3v,b3v,b3v};
            PRIO_HI();
            MFMA(A00, as0, w0); MFMA(A10, as1, w0);
            MFMA(A01, as0, w1); MFMA(A11, as1, w1);
            MFMA(A02, as0, w2); MFMA(A12, as1, w2);
            MFMA(A03, as0, w3); MFMA(A13, as1, w3);
            PRIO_LO();
#pragma unroll
            for (int r2 = 0; r2 < 4; ++r2) {
              const int row = (kg * 4 + r2) * HSTR;
              s_workA[row + (nbase + 0) * 16 + ln16] = f2b(fmaxf(A00[r2], 0.f));
              s_workA[row + (nbase + 1) * 16 + ln16] = f2b(fmaxf(A01[r2], 0.f));
              s_workA[row + (nbase + 2) * 16 + ln16] = f2b(fmaxf(A02[r2], 0.f));
              s_workA[row + (nbase + 3) * 16 + ln16] = f2b(fmaxf(A03[r2], 0.f));
              s_workB[row + (nbase + 0) * 16 + ln16] = f2b(fmaxf(A10[r2], 0.f));
              s_workB[row + (nbase + 1) * 16 + ln16] = f2b(fmaxf(A11[r2], 0.f));
              s_workB[row + (nbase + 2) * 16 + ln16] = f2b(fmaxf(A12[r2], 0.f));
              s_workB[row + (nbase + 3) * 16 + ln16] = f2b(fmaxf(A13[r2], 0.f));
            }
          }
        }
        {  // G3 dual + softmax (batched B, staggered h pairs)
#pragma unroll
          for (int nb = 0; nb < 2; ++nb) {
            const int n = nb * 16 + ln16;
            const s16x8 w0 = *(const s16x8*)&wsc[WC_PTA + n * 128 + 0 * 32 + k0];
            const s16x8 w1 = *(const s16x8*)&wsc[WC_PTA + n * 128 + 1 * 32 + k0];
            const s16x8 w2 = *(const s16x8*)&wsc[WC_PTA + n * 128 + 2 * 32 + k0];
            const s16x8 w3 = *(const s16x8*)&wsc[WC_PTA + n * 128 + 3 * 32 + k0];
            const float bias = bh2[n];
            f32x4 acc0 = {bias, bias, bias, bias};
            f32x4 acc1 = {bias, bias, bias, bias};
            PRIO_HI();
            {
              const s16x8 h0 = *(const s16x8*)&s_workA[ln16 * HSTR + 0 * 32 + k0];
              const s16x8 h1 = *(const s16x8*)&s_workB[ln16 * HSTR + 0 * 32 + k0];
              MFMA(acc0, h0, w0); MFMA(acc1, h1, w0);
            }
            {
              const s16x8 h0 = *(const s16x8*)&s_workA[ln16 * HSTR + 1 * 32 + k0];
              const s16x8 h1 = *(const s16x8*)&s_workB[ln16 * HSTR + 1 * 32 + k0];
              MFMA(acc0, h0, w1); MFMA(acc1, h1, w1);
            }
            {
              const s16x8 h0 = *(const s16x8*)&s_workA[ln16 * HSTR + 2 * 32 + k0];
              const s16x8 h1 = *(const s16x8*)&s_workB[ln16 * HSTR + 2 * 32 + k0];
              MFMA(acc0, h0, w2); MFMA(acc1, h1, w2);
            }
            {
              const s16x8 h0 = *(const s16x8*)&s_workA[ln16 * HSTR + 3 * 32 + k0];
              const s16x8 h1 = *(const s16x8*)&s_workB[ln16 * HSTR + 3 * 32 + k0];
              MFMA(acc0, h0, w3); MFMA(acc1, h1, w3);
            }
            PRIO_LO();
            const f32x4 rp0 = nb ? rpe01 : rpe00;
            const f32x4 rp1 = nb ? rpe11 : rpe10;
            float mx = fmaxf(fmaxf(acc0[0], acc0[1]), fmaxf(acc0[2], acc0[3]));
            mx = fmaxf(mx, __shfl_xor(mx, 16));
            mx = fmaxf(mx, __shfl_xor(mx, 32));
            float sum = 0.f, o = 0.f;
#pragma unroll
            for (int r2 = 0; r2 < 4; ++r2) {
              const int j = kg * 4 + r2;
              const float e = __expf(acc0[r2] - mx);
              sum += e;
              o = fmaf(e, b2f(s_vb[j * 32 + n]) + rp0[r2], o);
            }
            sum += __shfl_xor(sum, 16); o += __shfl_xor(o, 16);
            sum += __shfl_xor(sum, 32); o += __shfl_xor(o, 32);
            if (kg == 0) s_featb[g][i0 * BSTR + n] = f2b(o / sum);
            float mx1 = fmaxf(fmaxf(acc1[0], acc1[1]), fmaxf(acc1[2], acc1[3]));
            mx1 = fmaxf(mx1, __shfl_xor(mx1, 16));
            mx1 = fmaxf(mx1, __shfl_xor(mx1, 32));
            float sum1 = 0.f, o1 = 0.f;
#pragma unroll
            for (int r2 = 0; r2 < 4; ++r2) {
              const int j = kg * 4 + r2;
              const float e = __expf(acc1[r2] - mx1);
              sum1 += e;
              o1 = fmaf(e, b2f(s_vb[j * 32 + n]) + rp1[r2], o1);
            }
            sum1 += __shfl_xor(sum1, 16); o1 += __shfl_xor(o1, 16);
            sum1 += __shfl_xor(sum1, 32); o1 += __shfl_xor(o1, 32);
            if (kg == 0) s_featb[g][i1 * BSTR + n] = f2b(o1 / sum1);
          }
        }
      }
    }
    // ---- kk / vvb for batch g ----
    {
      const s16x8 af = *(const s16x8*)&s_featb[g][ln16 * BSTR + k0];
      const s16x8 wk0 = *(const s16x8*)&ws[WKK + (0 * 16 + ln16) * 32 + k0];
      const s16x8 wk1 = *(const s16x8*)&ws[WKK + (1 * 16 + ln16) * 32 + k0];
      const s16x8 wv0 = *(const s16x8*)&ws[WVV + (0 * 16 + ln16) * 32 + k0];
      const s16x8 wv1 = *(const s16x8*)&ws[WVV + (1 * 16 + ln16) * 32 + k0];
      const float bk0 = p.cak_b[ln16], bk1 = p.cak_b[16 + ln16];
      const float bv0 = p.cav_b[ln16], bv1 = p.cav_b[16 + ln16];
      f32x4 K0 = {bk0,bk0,bk0,bk0}, K1 = {bk1,bk1,bk1,bk1};
      f32x4 V0 = {bv0,bv0,bv0,bv0}, V1 = {bv1,bv1,bv1,bv1};
      PRIO_HI();
      MFMA(K0, af, wk0); MFMA(K1, af, wk1); MFMA(V0, af, wv0); MFMA(V1, af, wv1);
      PRIO_LO();
#pragma unroll
      for (int r2 = 0; r2 < 4; ++r2) {
        const int row = kg * 4 + r2;
        s_ub[g][row * 32 + ln16] = f2b(K0[r2]);
        s_ub[g][row * 32 + 16 + ln16] = f2b(K1[r2]);
        s_ub[g][512 + row * 32 + ln16] = f2b(V0[r2]);
        s_ub[g][512 + row * 32 + 16 + ln16] = f2b(V1[r2]);
      }
    }
  }

  // ================= Phase D: both batches dual-streamed =================
  {
    const float* b2d = p.cap_b2;
    const float* bc1 = p.caa_b1;
    const float* bc2 = p.caa_b2;
    const float* fw1 = p.fw1; const float* fw2 = p.fw2; const float* fw3 = p.fw3;
    const float* cqw = p.caq_w;
    const float* iw1 = p.im_w1; const float* iw2 = p.im_w2; const float* iw3 = p.im_w3;
    const unsigned short* wsd = ws;
    for (int s = 0; s <= 8; ++s) {
      asm volatile("" : "+s"(b2d), "+s"(bc1), "+s"(bc2), "+s"(wsd));
      asm volatile("" : "+s"(fw1), "+s"(fw2), "+s"(fw3), "+s"(cqw), "+s"(iw1), "+s"(iw2), "+s"(iw3));
      float rv0 = 0.f, rv1 = 0.f, rv2 = 0.f;
      // rel: lanes 0-15 batch0, lanes 32-47 batch1
      if (s < 8 && lh < 16) {
        const int k = lh;
        const float r0 = s_coords[gH][k * 3 + 0] - s_op[gH][0];
        const float r1 = s_coords[gH][k * 3 + 1] - s_op[gH][1];
        const float r2 = s_coords[gH][k * 3 + 2] - s_op[gH][2];
        const float rd = sqrtf(r0 * r0 + r1 * r1 + r2 * r2);
        const float inv = 1.f / rd;
        rv0 = r0 * inv; rv1 = r1 * inv; rv2 = r2 * inv;
        s_reld[gH][k] = rd;
        s_relv[gH][k * 3 + 0] = rv0; s_relv[gH][k * 3 + 1] = rv1; s_relv[gH][k * 3 + 2] = rv2;
        p.o_ld[(b0 + gH) * 128 + s * 16 + k] = rd;
      }
      {  // secA dual: hv for both batches, 4-n-tile groups
        float c00, c01, c02, c10, c11, c12;
        if (s < 8) {
          c00 = s_coords[0][ln16 * 3 + 0] - s_op[0][0];
          c01 = s_coords[0][ln16 * 3 + 1] - s_op[0][1];
          c02 = s_coords[0][ln16 * 3 + 2] - s_op[0][2];
          c10 = s_coords[1][ln16 * 3 + 0] - s_op[1][0];
          c11 = s_coords[1][ln16 * 3 + 1] - s_op[1][1];
          c12 = s_coords[1][ln16 * 3 + 2] - s_op[1][2];
        } else {
          const float rd0 = s_reld[0][ln16], rd1 = s_reld[1][ln16];
          c00 = s_relv[0][ln16 * 3 + 0] * rd0; c01 = s_relv[0][ln16 * 3 + 1] * rd0;
          c02 = s_relv[0][ln16 * 3 + 2] * rd0;
          c10 = s_relv[1][ln16 * 3 + 0] * rd1; c11 = s_relv[1][ln16 * 3 + 1] * rd1;
          c12 = s_relv[1][ln16 * 3 + 2] * rd1;
        }
        union { s16x8 v; unsigned u[4]; } cv0, cv1;
        cv0.u[0] = (kg == 0) ? pack2(c00, c01) : 0u;
        cv0.u[1] = (kg == 0) ? pack2(c02, 1.0f) : 0u;
        cv0.u[2] = 0u; cv0.u[3] = 0u;
        cv1.u[0] = (kg == 0) ? pack2(c10, c11) : 0u;
        cv1.u[1] = (kg == 0) ? pack2(c12, 1.0f) : 0u;
        cv1.u[2] = 0u; cv1.u[3] = 0u;
        const s16x8 af0 = cv0.v, af1 = cv1.v;
#pragma unroll
        for (int g2b = 0; g2b < 2; ++g2b) {
          const int nbase = g2b * 4;
          const s16x8 w0 = *(const s16x8*)&wsd[WH_CAP + ((nbase + 0) * 16 + ln16) * 32 + k0];
          const s16x8 w1 = *(const s16x8*)&wsd[WH_CAP + ((nbase + 1) * 16 + ln16) * 32 + k0];
          const s16x8 w2 = *(const s16x8*)&wsd[WH_CAP + ((nbase + 2) * 16 + ln16) * 32 + k0];
          const s16x8 w3 = *(const s16x8*)&wsd[WH_CAP + ((nbase + 3) * 16 + ln16) * 32 + k0];
          f32x4 A00 = {0.f,0.f,0.f,0.f}, A01 = {0.f,0.f,0.f,0.f};
          f32x4 A02 = {0.f,0.f,0.f,0.f}, A03 = {0.f,0.f,0.f,0.f};
          f32x4 A10 = {0.f,0.f,0.f,0.f}, A11 = {0.f,0.f,0.f,0.f};
          f32x4 A12 = {0.f,0.f,0.f,0.f}, A13 = {0.f,0.f,0.f,0.f};
          PRIO_HI();
          MFMA(A00, af0, w0); MFMA(A10, af1, w0);
          MFMA(A01, af0, w1); MFMA(A11, af1, w1);
          MFMA(A02, af0, w2); MFMA(A12, af1, w2);
          MFMA(A03, af0, w3); MFMA(A13, af1, w3);
          PRIO_LO();
#pragma unroll
          for (int r2 = 0; r2 < 4; ++r2) {
            const int row = (kg * 4 + r2) * HSTR;
            s_workA[row + (nbase + 0) * 16 + ln16] = f2b(fmaxf(A00[r2], 0.f));
            s_workA[row + (nbase + 1) * 16 + ln16] = f2b(fmaxf(A01[r2], 0.f));
            s_workA[row + (nbase + 2) * 16 + ln16] = f2b(fmaxf(A02[r2], 0.f));
            s_workA[row + (nbase + 3) * 16 + ln16] = f2b(fmaxf(A03[r2], 0.f));
            s_workB[row + (nbase + 0) * 16 + ln16] = f2b(fmaxf(A10[r2], 0.f));
            s_workB[row + (nbase + 1) * 16 + ln16] = f2b(fmaxf(A11[r2], 0.f));
            s_workB[row + (nbase + 2) * 16 + ln16] = f2b(fmaxf(A12[r2], 0.f));
            s_workB[row + (nbase + 3) * 16 + ln16] = f2b(fmaxf(A13[r2], 0.f));
          }
        }
      }
      {  // qq chain: half gH computes its batch (width-32 shuffles in-half)
        const int h = lh;
        float opc0, opc1, opc2;
        if (s < 8) {
          const float cum = s_cum[gH];
          opc0 = s_qry[gH][0] * cum; opc1 = s_qry[gH][1] * cum; opc2 = s_qry[gH][2] * cum;
        } else {
          opc0 = s_op[gH][0]; opc1 = s_op[gH][1]; opc2 = s_op[gH][2];
        }
        float v1 = fmaxf(fmaf(opc0, fw1[h],
                      fmaf(opc1, fw1[32 + h],
                      fmaf(opc2, fw1[64 + h], p.fb1[h]))), 0.f);
        float a = p.fb2[h];
        for (int i2 = 0; i2 < 32; ++i2) a = fmaf(__shfl(v1, i2, 32), fw2[i2 * 32 + h], a);
        const float v2 = fmaxf(a, 0.f);
        a = p.fb3[h];
        for (int i2 = 0; i2 < 32; ++i2) a = fmaf(__shfl(v2, i2, 32), fw3[i2 * 32 + h], a);
        const float opf = a;
        a = p.caq_b[h];
        for (int i2 = 0; i2 < 32; ++i2) a = fmaf(__shfl(opf, i2, 32), cqw[i2 * 32 + h], a);
        s_qq[gH][h] = a;
      }
      f32x4 pe00, pe01, pe10, pe11;
      {  // secB dual: batched B, staggered A pairs
#pragma unroll
        for (int nb = 0; nb < 2; ++nb) {
          const int n = nb * 16 + ln16;
          const s16x8 w0 = *(const s16x8*)&wsd[WA_CAP + n * 128 + 0 * 32 + k0];
          const s16x8 w1 = *(const s16x8*)&wsd[WA_CAP + n * 128 + 1 * 32 + k0];
          const s16x8 w2 = *(const s16x8*)&wsd[WA_CAP + n * 128 + 2 * 32 + k0];
          const s16x8 w3 = *(const s16x8*)&wsd[WA_CAP + n * 128 + 3 * 32 + k0];
          const float bias = b2d[n];
          f32x4 acc0 = {bias, bias, bias, bias};
          f32x4 acc1 = {bias, bias, bias, bias};
          PRIO_HI();
          {
            const s16x8 a0 = *(const s16x8*)&s_workA[ln16 * HSTR + 0 * 32 + k0];
            const s16x8 a1 = *(const s16x8*)&s_workB[ln16 * HSTR + 0 * 32 + k0];
            MFMA(acc0, a0, w0); MFMA(acc1, a1, w0);
          }
          {
            const s16x8 a0 = *(const s16x8*)&s_workA[ln16 * HSTR + 1 * 32 + k0];
            const s16x8 a1 = *(const s16x8*)&s_workB[ln16 * HSTR + 1 * 32 + k0];
            MFMA(acc0, a0, w1); MFMA(acc1, a1, w1);
          }
          {
            const s16x8 a0 = *(const s16x8*)&s_workA[ln16 * HSTR + 2 * 32 + k0];
            const s16x8 a1 = *(const s16x8*)&s_workB[ln16 * HSTR + 2 * 32 + k0];
            MFMA(acc0, a0, w2); MFMA(acc1, a1, w2);
          }
          {
            const s16x8 a0 = *(const s16x8*)&s_workA[ln16 * HSTR + 3 * 32 + k0];
            const s16x8 a1 = *(const s16x8*)&s_workB[ln16 * HSTR + 3 * 32 + k0];
            MFMA(acc0, a0, w3); MFMA(acc1, a1, w3);
          }
          PRIO_LO();
          if (nb == 0) { pe00 = acc0; pe10 = acc1; }
          else { pe01 = acc0; pe11 = acc1; }
#pragma unroll
          for (int r2 = 0; r2 < 4; ++r2) {
            const int row = kg * 4 + r2;
            s_simbA[row * BSTR + n] =
              f2b(s_qq[0][n] - b2f(s_ub[0][row * 32 + n]) + acc0[r2]);
            s_simbB[row * BSTR + n] =
              f2b(s_qq[1][n] - b2f(s_ub[1][row * 32 + n]) + acc1[r2]);
          }
        }
      }
      {  // secC dual: 4-n-tile groups
        const s16x8 as0 = *(const s16x8*)&s_simbA[ln16 * BSTR + k0];
        const s16x8 as1 = *(const s16x8*)&s_simbB[ln16 * BSTR + k0];
#pragma unroll
        for (int g2b = 0; g2b < 2; ++g2b) {
          const int nbase = g2b * 4;
          const s16x8 w0 = *(const s16x8*)&wsd[WB_CAA + ((nbase + 0) * 16 + ln16) * 32 + k0];
          const s16x8 w1 = *(const s16x8*)&wsd[WB_CAA + ((nbase + 1) * 16 + ln16) * 32 + k0];
          const s16x8 w2 = *(const s16x8*)&wsd[WB_CAA + ((nbase + 2) * 16 + ln16) * 32 + k0];
          const s16x8 w3 = *(const s16x8*)&wsd[WB_CAA + ((nbase + 3) * 16 + ln16) * 32 + k0];
          const float b0v = bc1[(nbase + 0) * 16 + ln16];
          const float b1v = bc1[(nbase + 1) * 16 + ln16];
          const float b2v = bc1[(nbase + 2) * 16 + ln16];
          const float b3v = bc1[(nbase + 3) * 16 + ln16];
          f32x4 A00 = {b0v,b0v,b0v,b0v}, A01 = {b1v,b1v,b1v,b1v};
          f32x4 A02 = {b2v,b2v,b2v,b2v}, A03 = {b3v,b3v,b3v,b3v};
          f32x4 A10 = {b0v,b0v,b0v,b0v}, A11 = {b1v,b1v,b1v,b1v};
          f32x4 A12 = {b2v,b2v,b2v,b2v}, A13 = {b3v,b3v,b3v,b3v};
          PRIO_HI();
          MFMA(A00, as0, w0); MFMA(A10, as1, w0);
          MFMA(A01, as0, w1); MFMA(A11, as1, w1);
          MFMA(A02, as0, w2); MFMA(A12, as1, w2);
          MFMA(A03, as0, w3); MFMA(A13, as1, w3);
          PRIO_LO();
#pragma unroll
          for (int r2 = 0; r2 < 4; ++r2) {
            const int row = (kg * 4 + r2) * HSTR;
            s_workA[row + (nbase + 0) * 16 + ln16] = f2b(fmaxf(A00[r2], 0.f));
            s_workA[row + (nbase + 1) * 16 + ln16] = f2b(fmaxf(A01[r2], 0.f));
            s_workA[row + (nbase + 2) * 16 + ln16] = f2b(fmaxf(A02[r2], 0.f));
            s_workA[row + (nbase + 3) * 16 + ln16] = f2b(fmaxf(A03[r2], 0.f));
            s_workB[row + (nbase + 0) * 16 + ln16] = f2b(fmaxf(A10[r2], 0.f));
            s_workB[row + (nbase + 1) * 16 + ln16] = f2b(fmaxf(A11[r2], 0.f));
            s_workB[row + (nbase + 2) * 16 + ln16] = f2b(fmaxf(A12[r2], 0.f));
            s_workB[row + (nbase + 3) * 16 + ln16] = f2b(fmaxf(A13[r2], 0.f));
          }
        }
      }
      {  // secD dual + softmax -> s_ca[g] (batched B, staggered h pairs)
#pragma unroll
        for (int nb = 0; nb < 2; ++nb) {
          const int n = nb * 16 + ln16;
          const s16x8 w0 = *(const s16x8*)&wsd[WC_CAA + n * 128 + 0 * 32 + k0];
          const s16x8 w1 = *(const s16x8*)&wsd[WC_CAA + n * 128 + 1 * 32 + k0];
          const s16x8 w2 = *(const s16x8*)&wsd[WC_CAA + n * 128 + 2 * 32 + k0];
          const s16x8 w3 = *(const s16x8*)&wsd[WC_CAA + n * 128 + 3 * 32 + k0];
          const float bias = bc2[n];
          f32x4 acc0 = {bias, bias, bias, bias};
          f32x4 acc1 = {bias, bias, bias, bias};
          PRIO_HI();
          {
            const s16x8 h0 = *(const s16x8*)&s_workA[ln16 * HSTR + 0 * 32 + k0];
            const s16x8 h1 = *(const s16x8*)&s_workB[ln16 * HSTR + 0 * 32 + k0];
            MFMA(acc0, h0, w0); MFMA(acc1, h1, w0);
          }
          {
            const s16x8 h0 = *(const s16x8*)&s_workA[ln16 * HSTR + 1 * 32 + k0];
            const s16x8 h1 = *(const s16x8*)&s_workB[ln16 * HSTR + 1 * 32 + k0];
            MFMA(acc0, h0, w1); MFMA(acc1, h1, w1);
          }
          {
            const s16x8 h0 = *(const s16x8*)&s_workA[ln16 * HSTR + 2 * 32 + k0];
            const s16x8 h1 = *(const s16x8*)&s_workB[ln16 * HSTR + 2 * 32 + k0];
            MFMA(acc0, h0, w2); MFMA(acc1, h1, w2);
          }
          {
            const s16x8 h0 = *(const s16x8*)&s_workA[ln16 * HSTR + 3 * 32 + k0];
            const s16x8 h1 = *(const s16x8*)&s_workB[ln16 * HSTR + 3 * 32 + k0];
            MFMA(acc0, h0, w3); MFMA(acc1, h1, w3);
          }
          PRIO_LO();
          const f32x4 rp0 = nb ? pe01 : pe00;
          const f32x4 rp1 = nb ? pe11 : pe10;
          float mx = fmaxf(fmaxf(acc0[0], acc0[1]), fmaxf(acc0[2], acc0[3]));
          mx = fmaxf(mx, __shfl_xor(mx, 16));
          mx = fmaxf(mx, __shfl_xor(mx, 32));
          float sum = 0.f, o = 0.f;
#pragma unroll
          for (int r2 = 0; r2 < 4; ++r2) {
            const int row = kg * 4 + r2;
            const float e = __expf(acc0[r2] - mx);
            sum += e;
            o = fmaf(e, b2f(s_ub[0][512 + row * 32 + n]) + rp0[r2], o);
          }
          sum += __shfl_xor(sum, 16); o += __shfl_xor(o, 16);
          sum += __shfl_xor(sum, 32); o += __shfl_xor(o, 32);
          if (kg == 0) s_ca[0][n] = o / sum;
          float mx1 = fmaxf(fmaxf(acc1[0], acc1[1]), fmaxf(acc1[2], acc1[3]));
          mx1 = fmaxf(mx1, __shfl_xor(mx1, 16));
          mx1 = fmaxf(mx1, __shfl_xor(mx1, 32));
          float sum1 = 0.f, o1 = 0.f;
#pragma unroll
          for (int r2 = 0; r2 < 4; ++r2) {
            const int row = kg * 4 + r2;
            const float e = __expf(acc1[r2] - mx1);
            sum1 += e;
            o1 = fmaf(e, b2f(s_ub[1][512 + row * 32 + n]) + rp1[r2], o1);
          }
          sum1 += __shfl_xor(sum1, 16); o1 += __shfl_xor(o1, 16);
          sum1 += __shfl_xor(sum1, 32); o1 += __shfl_xor(o1, 32);
          if (kg == 0) s_ca[1][n] = o1 / sum1;
        }
      }
      {  // im / ep chain: half gH = its batch; width-32 shuffles in-half
        const int h = lh;
        const int bD = b0 + gH;
        const float cav = s_ca[gH][h];
        if (s < 8) {
          float a = p.im_b1[h];
          for (int i2 = 0; i2 < 32; ++i2) a = fmaf(__shfl(cav, i2, 32), iw1[i2 * 32 + h], a);
          const float m1 = fmaxf(a, 0.f);
          a = p.im_b2[h];
          for (int i2 = 0; i2 < 32; ++i2) a = fmaf(__shfl(m1, i2, 32), iw2[i2 * 32 + h], a);
          const float m2 = fmaxf(a, 0.f);
          float p0 = m2 * iw3[h * 3 + 0];
          float p1 = m2 * iw3[h * 3 + 1];
          float p2 = m2 * iw3[h * 3 + 2];
#pragma unroll
          for (int m = 1; m < 32; m <<= 1) {
            p0 += __shfl_xor(p0, m, 32);
            p1 += __shfl_xor(p1, m, 32);
            p2 += __shfl_xor(p2, m, 32);
          }
          p0 += p.im_b3[0]; p1 += p.im_b3[1]; p2 += p.im_b3[2];
          const float step = sqrtf(p0 * p0 + p1 * p1 + p2 * p2);
          const float cum = s_cum[gH];
          const float opc0 = s_qry[gH][0] * cum;
          const float opc1 = s_qry[gH][1] * cum;
          const float opc2 = s_qry[gH][2] * cum;
          const float inv = 1.f / step;
          const float tg0 = p0 * inv, tg1 = p1 * inv, tg2 = p2 * inv;
          if (lh == 0) {
            p.o_ms[bD * 8 + s] = step;
            p.o_ip[(bD * 8 + s) * 3 + 0] = opc0 + p0;
            s_op[gH][0] = opc0 + s_qry[gH][0] * step;
          } else if (lh == 1) {
            p.o_ip[(bD * 8 + s) * 3 + 1] = opc1 + p1;
            s_op[gH][1] = opc1 + s_qry[gH][1] * step;
          } else if (lh == 2) {
            p.o_ip[(bD * 8 + s) * 3 + 2] = opc2 + p2;
            s_op[gH][2] = opc2 + s_qry[gH][2] * step;
          } else if (lh == 3) {
            s_cum[gH] = cum + step;
          }
          if (lh < 16) {
            p.o_cs[bD * 128 + s * 16 + lh] = tg0 * rv0 + tg1 * rv1 + tg2 * rv2;
          }
        } else {
          float a = p.ep_b1[h];
          for (int i2 = 0; i2 < 32; ++i2) a = fmaf(__shfl(cav, i2, 32), p.ep_w1[i2 * 32 + h], a);
          a = fmaf(s_qry[gH][0], p.ep_w1[1024 + h], a);
          a = fmaf(s_qry[gH][1], p.ep_w1[1056 + h], a);
          a = fmaf(s_qry[gH][2], p.ep_w1[1088 + h], a);
          const float e1 = fmaxf(a, 0.f);
          a = p.ep_b2[h];
          for (int i2 = 0; i2 < 32; ++i2) a = fmaf(__shfl(e1, i2, 32), p.ep_w2[i2 * 32 + h], a);
          const float e2 = fmaxf(a, 0.f);
          float pp = e2 * p.ep_w3[h];
#pragma unroll
          for (int m = 1; m < 32; m <<= 1) pp += __shfl_xor(pp, m, 32);
          if (lh == 0) {
            p.o_eps[bD] = pp + p.ep_b3[0];
            p.o_cum[bD] = s_cum[gH];
          }
        }
      }
    }
  }
}

extern "C" void kernel_launch(void* const* d_in, const int* in_sizes, int n_in,
                              void* d_out, int out_size, void* d_ws, size_t ws_size,
                              hipStream_t stream) {
  Params p;
  const float** f = (const float**)(void*)&p;
  for (int i = 0; i < 43; ++i) f[i] = (const float*)d_in[i];
  float* out = (float*)d_out;
  p.o_ld  = out;
  p.o_ms  = out + OFF_MS;
  p.o_cs  = out + OFF_CS;
  p.o_ip  = out + OFF_IP;
  p.o_cum = out + OFF_CUM;
  p.o_eps = out + OFF_EPS;
  unsigned short* ws = (unsigned short*)d_ws;
  prep_kernel<<<dim3(16), dim3(256), 0, stream>>>(p, ws);
  puray_kernel<<<dim3(2048), dim3(64), 0, stream>>>(p, ws);
}